// Round 14
// baseline (612.987 us; speedup 1.0000x reference)
//
#include <hip/hip_runtime.h>
#include <hip/hip_bf16.h>

#define E_  8
#define M_  1024
#define K_  4096
#define N_  2048
#define N2_ 1024

typedef unsigned short u16;
typedef unsigned int   u32;

typedef __bf16 bf16x8 __attribute__((ext_vector_type(8)));
typedef float  f32x4  __attribute__((ext_vector_type(4)));

union FragU { uint4 u; bf16x8 v; };

__device__ __forceinline__ u16 f2bfu(float f){
  union { __hip_bfloat16 h; u16 u; } c;
  c.h = __float2bfloat16(f);   // RNE
  return c.u;
}
__device__ __forceinline__ u32 pack2(float a, float b){
  return (u32)f2bfu(a) | ((u32)f2bfu(b) << 16);
}
__device__ __forceinline__ float bf2f(u16 u){
  u32 x = ((u32)u) << 16;
  return __uint_as_float(x);
}
// f32 whose bits are the RNE-bf16 of f (low mantissa zero) — matches bf16 ref.
__device__ __forceinline__ float bf16val(float f){
  return bf2f(f2bfu(f));
}
__device__ __forceinline__ float fp8_round(float x){
  float ax = fabsf(x);
  if (ax < 0.015625f){
    return rintf(x * 512.0f) * (1.0f/512.0f);
  }
  u32 u = __float_as_uint(x);
  u32 lsb = (u >> 20) & 1u;
  u += 0x7FFFFu + lsb;
  u &= 0xFFF00000u;
  return __uint_as_float(u);
}

// ---------------------------------------------------------------------------
// Grouped masked MFMA GEMM, BK=32 double-buffered (LDS 32 KiB -> 4-5 blocks/CU).
// C[e][m][n] = sum_k A[e][m][k]*B[e][n][k], dequant scales folded at staging.
// AMODE 0: A fp32(fp8)+Ascale; C -> gateup bf16 u16 (internal, our coords)
// AMODE 1: A bf16 (a2);        C -> d_out as FLOAT32; masked rows -> 0.0f.
// ---------------------------------------------------------------------------
template<int AMODE, int KD, int ND>
__global__ __launch_bounds__(256, 4) void gemm_grouped(
    const void* __restrict__ Aptr_, const float* __restrict__ Ascale,
    const float* __restrict__ Bptr, const float* __restrict__ Wscale,
    const int* __restrict__ masked_m, void* __restrict__ Cout)
{
  constexpr int BK  = 32;
  constexpr int KT  = KD / BK;
  constexpr int NKB = KD / 128;
  const int tn = blockIdx.x, tm = blockIdx.y, e = blockIdx.z;
  const int m0 = tm * 128, n0 = tn * 128;
  const int me = masked_m[e];
  const int tid = threadIdx.x;

  u16*   const Cu = (u16*)Cout;      // AMODE 0: bf16 u16 buffer
  float* const Cf = (float*)Cout;    // AMODE 1: float32 buffer

  if (m0 >= me){
    if constexpr (AMODE == 1){
      const uint4 z = make_uint4(0u,0u,0u,0u);
      #pragma unroll
      for (int q = 0; q < 16; ++q){
        int idx = tid + 256*q;            // 128 rows x 32 uint4 (128 f32)
        int r = idx >> 5, c = idx & 31;
        *reinterpret_cast<uint4*>(Cf + ((size_t)e*M_ + m0 + r)*ND + n0 + c*4) = z;
      }
    }
    return;
  }

  __shared__ u16 sA[2][128*32];
  __shared__ u16 sB[2][128*32];

  const int rrow = tid >> 2;   // 0..63: row within 64-row pass group
  const int kq   = tid & 3;    // 16B chunk (8 bf16) within a 32-elem row
  const float* Af = (const float*)Aptr_;
  const u16*   Au = (const u16*)Aptr_;

  float4 rA[4], rB[4];
  uint4  rAu[2];
  float  rAs[2];
  float  sWv = 0.f;

  auto STAGE_LOAD = [&](int kt){
    const int k0 = kt * BK;
    const int kb = k0 >> 7;
    sWv = Wscale[((size_t)e*(ND/128) + tn)*NKB + kb];
    #pragma unroll
    for (int p = 0; p < 2; ++p){
      const int r = p*64 + rrow;
      if constexpr (AMODE == 0){
        const float* ap = Af + ((size_t)e*M_ + m0 + r)*KD + k0 + kq*8;
        rA[2*p]   = *reinterpret_cast<const float4*>(ap);
        rA[2*p+1] = *reinterpret_cast<const float4*>(ap + 4);
        rAs[p]    = Ascale[((size_t)e*M_ + m0 + r)*NKB + kb];
      } else {
        const u16* ap = Au + ((size_t)e*M_ + m0 + r)*KD + k0 + kq*8;
        rAu[p] = *reinterpret_cast<const uint4*>(ap);
      }
      const float* bp = Bptr + ((size_t)e*ND + n0 + r)*KD + k0 + kq*8;
      rB[2*p]   = *reinterpret_cast<const float4*>(bp);
      rB[2*p+1] = *reinterpret_cast<const float4*>(bp + 4);
    }
  };

  auto STAGE_WRITE = [&](int buf){
    #pragma unroll
    for (int p = 0; p < 2; ++p){
      const int r   = p*64 + rrow;
      const int dst = r*32 + ((kq ^ ((r >> 1) & 3)) * 8);  // XOR-swizzled chunk
      if constexpr (AMODE == 0){
        const float s = rAs[p];
        uint4 w;
        w.x = pack2(rA[2*p].x * s,   rA[2*p].y * s);
        w.y = pack2(rA[2*p].z * s,   rA[2*p].w * s);
        w.z = pack2(rA[2*p+1].x * s, rA[2*p+1].y * s);
        w.w = pack2(rA[2*p+1].z * s, rA[2*p+1].w * s);
        *reinterpret_cast<uint4*>(&sA[buf][dst]) = w;
      } else {
        *reinterpret_cast<uint4*>(&sA[buf][dst]) = rAu[p];
      }
      uint4 wb;
      wb.x = pack2(rB[2*p].x * sWv,   rB[2*p].y * sWv);
      wb.y = pack2(rB[2*p].z * sWv,   rB[2*p].w * sWv);
      wb.z = pack2(rB[2*p+1].x * sWv, rB[2*p+1].y * sWv);
      wb.w = pack2(rB[2*p+1].z * sWv, rB[2*p+1].w * sWv);
      *reinterpret_cast<uint4*>(&sB[buf][dst]) = wb;
    }
  };

  const int lane = tid & 63, wid = tid >> 6;
  const int wm = wid >> 1, wn = wid & 1;   // 2x2 waves, each owns 64x64
  const int fr = lane & 15, kg = lane >> 4;

  f32x4 acc[4][4];
  #pragma unroll
  for (int i = 0; i < 4; ++i)
    #pragma unroll
    for (int j = 0; j < 4; ++j)
      acc[i][j] = (f32x4){0.f, 0.f, 0.f, 0.f};

  auto COMPUTE = [&](int buf){
    FragU av[4], bv[4];
    #pragma unroll
    for (int i = 0; i < 4; ++i){
      const int r  = wm*64 + i*16 + fr;
      const int ch = kg ^ ((r >> 1) & 3);
      av[i].u = *reinterpret_cast<const uint4*>(&sA[buf][r*32 + ch*8]);
    }
    #pragma unroll
    for (int j = 0; j < 4; ++j){
      const int r  = wn*64 + j*16 + fr;
      const int ch = kg ^ ((r >> 1) & 3);
      bv[j].u = *reinterpret_cast<const uint4*>(&sB[buf][r*32 + ch*8]);
    }
    #pragma unroll
    for (int i = 0; i < 4; ++i)
      #pragma unroll
      for (int j = 0; j < 4; ++j)
        acc[i][j] = __builtin_amdgcn_mfma_f32_16x16x32_bf16(av[i].v, bv[j].v, acc[i][j], 0, 0, 0);
  };

  STAGE_LOAD(0);
  STAGE_WRITE(0);
  __syncthreads();
  int cur = 0;
  for (int kt = 0; kt < KT; ++kt){
    if (kt + 1 < KT) STAGE_LOAD(kt + 1);   // issue next loads (hide under MFMA)
    COMPUTE(cur);
    if (kt + 1 < KT) STAGE_WRITE(cur ^ 1); // other buffer: no hazard
    __syncthreads();
    cur ^= 1;
  }

  #pragma unroll
  for (int i = 0; i < 4; ++i){
    #pragma unroll
    for (int j = 0; j < 4; ++j){
      #pragma unroll
      for (int r = 0; r < 4; ++r){
        const int gm = m0 + wm*64 + i*16 + kg*4 + r;
        const int gn = n0 + wn*64 + j*16 + fr;
        if constexpr (AMODE == 0){
          if (gm < me) Cu[((size_t)e*M_ + gm)*ND + gn] = f2bfu(acc[i][j][r]);
        } else {
          const float v = (gm < me) ? bf16val(acc[i][j][r]) : 0.0f;
          Cf[((size_t)e*M_ + gm)*ND + gn] = v;
        }
      }
    }
  }
}

// SiLU(gate)*up, per-128 amax -> scale, fp8 RNE quant, store dequantized bf16.
__global__ __launch_bounds__(128) void act_quant_kernel(
    const u16* __restrict__ gu, const int* __restrict__ masked_m,
    u16* __restrict__ a2)
{
  const int m = blockIdx.x, e = blockIdx.y;
  if (m >= masked_m[e]) return;
  const int t = threadIdx.x;
  const u16* row = gu + ((size_t)e*M_ + m)*N_;
  uint4 g4 = *reinterpret_cast<const uint4*>(row + t*8);
  uint4 u4 = *reinterpret_cast<const uint4*>(row + N2_ + t*8);
  u32 gp[4] = {g4.x, g4.y, g4.z, g4.w};
  u32 up[4] = {u4.x, u4.y, u4.z, u4.w};

  float x[8];
  #pragma unroll
  for (int w = 0; w < 4; ++w){
    float g0 = bf2f((u16)(gp[w] & 0xffffu));
    float g1 = bf2f((u16)(gp[w] >> 16));
    float u0 = bf2f((u16)(up[w] & 0xffffu));
    float u1 = bf2f((u16)(up[w] >> 16));
    x[2*w]   = g0 / (1.0f + expf(-g0)) * u0;
    x[2*w+1] = g1 / (1.0f + expf(-g1)) * u1;
  }

  float amax = 0.f;
  #pragma unroll
  for (int k = 0; k < 8; ++k) amax = fmaxf(amax, fabsf(x[k]));
  #pragma unroll
  for (int o = 8; o > 0; o >>= 1) amax = fmaxf(amax, __shfl_xor(amax, o, 16));
  const float scale = fmaxf(amax, 1e-10f) / 448.0f;

  u32 hh[4];
  #pragma unroll
  for (int w = 0; w < 4; ++w){
    float d0 = fp8_round(x[2*w]   / scale) * scale;
    float d1 = fp8_round(x[2*w+1] / scale) * scale;
    hh[w] = pack2(d0, d1);
  }
  uint4 o4 = make_uint4(hh[0], hh[1], hh[2], hh[3]);
  *reinterpret_cast<uint4*>(a2 + ((size_t)e*M_ + m)*N2_ + t*8) = o4;
}

extern "C" void kernel_launch(void* const* d_in, const int* in_sizes, int n_in,
                              void* d_out, int out_size, void* d_ws, size_t ws_size,
                              hipStream_t stream)
{
  const float* hs   = (const float*)d_in[0];   // (E,M,K) fp32 holding fp8 values
  const float* hss  = (const float*)d_in[1];   // (E,M,K/128)
  const int*   mm   = (const int*)d_in[2];     // (E,)
  const float* w13  = (const float*)d_in[4];   // (E,N,K)
  const float* w13s = (const float*)d_in[5];   // (E,N/128,K/128)
  const float* w2   = (const float*)d_in[6];   // (E,K,N2)
  const float* w2s  = (const float*)d_in[7];   // (E,K/128,N2/128)

  // d_out is a FLOAT32 buffer (checker reads bf16 high-halves / f32 values).
  // gateup (bf16 u16, 67 MB) lives in its first half, consumed by act_quant
  // before gemm2 overwrites the whole buffer with f32 output.
  u16* gu = (u16*)d_out;
  u16* a2 = (u16*)d_ws;          // a2 (E,M,N2) bf16 in d_ws (16.78 MB)

  gemm_grouped<0, K_, N_><<<dim3(N_/128, M_/128, E_), dim3(256), 0, stream>>>(
      hs, hss, w13, w13s, mm, gu);
  act_quant_kernel<<<dim3(M_, E_), dim3(128), 0, stream>>>(gu, mm, a2);
  gemm_grouped<1, N2_, K_><<<dim3(K_/128, M_/128, E_), dim3(256), 0, stream>>>(
      a2, nullptr, w2, w2s, mm, d_out);
}

// Round 15
// 396.328 us; speedup vs baseline: 1.5467x; 1.5467x over previous
//
#include <hip/hip_runtime.h>
#include <hip/hip_bf16.h>

#define E_  8
#define M_  1024
#define K_  4096
#define N_  2048
#define N2_ 1024

typedef unsigned short u16;
typedef unsigned int   u32;

typedef __bf16 bf16x8 __attribute__((ext_vector_type(8)));
typedef float  f32x4  __attribute__((ext_vector_type(4)));

union FragU { uint4 u; bf16x8 v; };

__device__ __forceinline__ u16 f2bfu(float f){
  union { __hip_bfloat16 h; u16 u; } c;
  c.h = __float2bfloat16(f);   // RNE
  return c.u;
}
__device__ __forceinline__ u32 pack2(float a, float b){
  return (u32)f2bfu(a) | ((u32)f2bfu(b) << 16);
}
__device__ __forceinline__ float bf2f(u16 u){
  u32 x = ((u32)u) << 16;
  return __uint_as_float(x);
}
// f32 whose bits are the RNE-bf16 of f (low mantissa zero) — matches bf16 ref.
__device__ __forceinline__ float bf16val(float f){
  return bf2f(f2bfu(f));
}
__device__ __forceinline__ float fp8_round(float x){
  float ax = fabsf(x);
  if (ax < 0.015625f){
    return rintf(x * 512.0f) * (1.0f/512.0f);
  }
  u32 u = __float_as_uint(x);
  u32 lsb = (u >> 20) & 1u;
  u += 0x7FFFFu + lsb;
  u &= 0xFFF00000u;
  return __uint_as_float(u);
}

// ---------------------------------------------------------------------------
// Grouped masked MFMA GEMM, 256x256 tile, BK=64, 512 threads (8 waves 2x4),
// double-buffered LDS (128 KiB), 2-barrier schedule.
// C[e][m][n] = sum_k A[e][m][k]*B[e][n][k], dequant scales folded at staging.
// AMODE 0: A fp32(fp8)+Ascale; C -> gateup bf16 u16 (internal)
// AMODE 1: A bf16 (a2);        C -> d_out as FLOAT32; masked rows -> 0.0f.
// ---------------------------------------------------------------------------
template<int AMODE, int KD, int ND>
__global__ __launch_bounds__(512, 2) void gemm_grouped(
    const void* __restrict__ Aptr_, const float* __restrict__ Ascale,
    const float* __restrict__ Bptr, const float* __restrict__ Wscale,
    const int* __restrict__ masked_m, void* __restrict__ Cout)
{
  constexpr int BK  = 64;
  constexpr int KT  = KD / BK;
  constexpr int NKB = KD / 128;
  const int tn = blockIdx.x, tm = blockIdx.y, e = blockIdx.z;
  const int m0 = tm * 256, n0 = tn * 256;
  const int me = masked_m[e];
  const int tid = threadIdx.x;

  u16*   const Cu = (u16*)Cout;      // AMODE 0: bf16 u16 buffer
  float* const Cf = (float*)Cout;    // AMODE 1: float32 buffer

  if (m0 >= me){
    if constexpr (AMODE == 1){
      const uint4 z = make_uint4(0u,0u,0u,0u);
      #pragma unroll
      for (int q = 0; q < 32; ++q){
        int idx = tid + 512*q;            // 256 rows x 64 uint4 (256 f32)
        int r = idx >> 6, c = idx & 63;
        *reinterpret_cast<uint4*>(Cf + ((size_t)e*M_ + m0 + r)*ND + n0 + c*4) = z;
      }
    }
    return;
  }

  __shared__ u16 sA[2][256*64];
  __shared__ u16 sB[2][256*64];

  const int rrow = tid >> 3;   // 0..63: row within 64-row pass group
  const int kq   = tid & 7;    // 16B chunk (8 bf16 / 4 fp32x2) within 64-elem row
  const float* Af = (const float*)Aptr_;
  const u16*   Au = (const u16*)Aptr_;

  float4 rA[8], rB[8];
  uint4  rAu[4];
  float  rAs[4];
  float  sWv[2] = {0.f, 0.f};

  auto STAGE_LOAD = [&](int kt){
    const int k0 = kt * BK;
    const int kb = k0 >> 7;
    sWv[0] = Wscale[((size_t)e*(ND/128) + tn*2 + 0)*NKB + kb];
    sWv[1] = Wscale[((size_t)e*(ND/128) + tn*2 + 1)*NKB + kb];
    #pragma unroll
    for (int p = 0; p < 4; ++p){
      const int r = p*64 + rrow;
      if constexpr (AMODE == 0){
        const float* ap = Af + ((size_t)e*M_ + m0 + r)*KD + k0 + kq*8;
        rA[2*p]   = *reinterpret_cast<const float4*>(ap);
        rA[2*p+1] = *reinterpret_cast<const float4*>(ap + 4);
        rAs[p]    = Ascale[((size_t)e*M_ + m0 + r)*NKB + kb];
      } else {
        const u16* ap = Au + ((size_t)e*M_ + m0 + r)*KD + k0 + kq*8;
        rAu[p] = *reinterpret_cast<const uint4*>(ap);
      }
      const float* bp = Bptr + ((size_t)e*ND + n0 + r)*KD + k0 + kq*8;
      rB[2*p]   = *reinterpret_cast<const float4*>(bp);
      rB[2*p+1] = *reinterpret_cast<const float4*>(bp + 4);
    }
  };

  auto STAGE_WRITE = [&](int buf){
    #pragma unroll
    for (int p = 0; p < 4; ++p){
      const int r   = p*64 + rrow;
      const int dst = r*64 + ((kq ^ (r & 7)) * 8);   // XOR-swizzled 16B chunk
      if constexpr (AMODE == 0){
        const float s = rAs[p];
        uint4 w;
        w.x = pack2(rA[2*p].x * s,   rA[2*p].y * s);
        w.y = pack2(rA[2*p].z * s,   rA[2*p].w * s);
        w.z = pack2(rA[2*p+1].x * s, rA[2*p+1].y * s);
        w.w = pack2(rA[2*p+1].z * s, rA[2*p+1].w * s);
        *reinterpret_cast<uint4*>(&sA[buf][dst]) = w;
      } else {
        *reinterpret_cast<uint4*>(&sA[buf][dst]) = rAu[p];
      }
      const float sw = sWv[p >> 1];
      uint4 wb;
      wb.x = pack2(rB[2*p].x * sw,   rB[2*p].y * sw);
      wb.y = pack2(rB[2*p].z * sw,   rB[2*p].w * sw);
      wb.z = pack2(rB[2*p+1].x * sw, rB[2*p+1].y * sw);
      wb.w = pack2(rB[2*p+1].z * sw, rB[2*p+1].w * sw);
      *reinterpret_cast<uint4*>(&sB[buf][dst]) = wb;
    }
  };

  const int lane = tid & 63, wid = tid >> 6;     // 8 waves
  const int wm = wid >> 2, wn = wid & 3;         // 2x4: wave tile 128(m) x 64(n)
  const int fr = lane & 15, kg = lane >> 4;

  f32x4 acc[8][4];
  #pragma unroll
  for (int i = 0; i < 8; ++i)
    #pragma unroll
    for (int j = 0; j < 4; ++j)
      acc[i][j] = (f32x4){0.f, 0.f, 0.f, 0.f};

  auto COMPUTE = [&](int buf){
    #pragma unroll
    for (int ks = 0; ks < 2; ++ks){
      FragU bv[4];
      #pragma unroll
      for (int j = 0; j < 4; ++j){
        const int r  = wn*64 + j*16 + fr;
        const int ch = (ks*4 + kg) ^ (r & 7);
        bv[j].u = *reinterpret_cast<const uint4*>(&sB[buf][r*64 + ch*8]);
      }
      #pragma unroll
      for (int i = 0; i < 8; ++i){
        const int r  = wm*128 + i*16 + fr;
        const int ch = (ks*4 + kg) ^ (r & 7);
        FragU av;
        av.u = *reinterpret_cast<const uint4*>(&sA[buf][r*64 + ch*8]);
        #pragma unroll
        for (int j = 0; j < 4; ++j)
          acc[i][j] = __builtin_amdgcn_mfma_f32_16x16x32_bf16(av.v, bv[j].v, acc[i][j], 0, 0, 0);
      }
    }
  };

  STAGE_LOAD(0);
  STAGE_WRITE(0);
  __syncthreads();
  int cur = 0;
  for (int kt = 0; kt < KT; ++kt){
    if (kt + 1 < KT) STAGE_LOAD(kt + 1);   // issue next loads (hide under MFMA)
    COMPUTE(cur);
    if (kt + 1 < KT) STAGE_WRITE(cur ^ 1); // other buffer: no hazard
    __syncthreads();
    cur ^= 1;
  }

  #pragma unroll
  for (int i = 0; i < 8; ++i){
    #pragma unroll
    for (int j = 0; j < 4; ++j){
      #pragma unroll
      for (int r = 0; r < 4; ++r){
        const int gm = m0 + wm*128 + i*16 + kg*4 + r;
        const int gn = n0 + wn*64 + j*16 + fr;
        if constexpr (AMODE == 0){
          if (gm < me) Cu[((size_t)e*M_ + gm)*ND + gn] = f2bfu(acc[i][j][r]);
        } else {
          const float v = (gm < me) ? bf16val(acc[i][j][r]) : 0.0f;
          Cf[((size_t)e*M_ + gm)*ND + gn] = v;
        }
      }
    }
  }
}

// SiLU(gate)*up, per-128 amax -> scale, fp8 RNE quant, store dequantized bf16.
__global__ __launch_bounds__(128) void act_quant_kernel(
    const u16* __restrict__ gu, const int* __restrict__ masked_m,
    u16* __restrict__ a2)
{
  const int m = blockIdx.x, e = blockIdx.y;
  if (m >= masked_m[e]) return;
  const int t = threadIdx.x;
  const u16* row = gu + ((size_t)e*M_ + m)*N_;
  uint4 g4 = *reinterpret_cast<const uint4*>(row + t*8);
  uint4 u4 = *reinterpret_cast<const uint4*>(row + N2_ + t*8);
  u32 gp[4] = {g4.x, g4.y, g4.z, g4.w};
  u32 up[4] = {u4.x, u4.y, u4.z, u4.w};

  float x[8];
  #pragma unroll
  for (int w = 0; w < 4; ++w){
    float g0 = bf2f((u16)(gp[w] & 0xffffu));
    float g1 = bf2f((u16)(gp[w] >> 16));
    float u0 = bf2f((u16)(up[w] & 0xffffu));
    float u1 = bf2f((u16)(up[w] >> 16));
    x[2*w]   = g0 / (1.0f + expf(-g0)) * u0;
    x[2*w+1] = g1 / (1.0f + expf(-g1)) * u1;
  }

  float amax = 0.f;
  #pragma unroll
  for (int k = 0; k < 8; ++k) amax = fmaxf(amax, fabsf(x[k]));
  #pragma unroll
  for (int o = 8; o > 0; o >>= 1) amax = fmaxf(amax, __shfl_xor(amax, o, 16));
  const float scale = fmaxf(amax, 1e-10f) / 448.0f;

  u32 hh[4];
  #pragma unroll
  for (int w = 0; w < 4; ++w){
    float d0 = fp8_round(x[2*w]   / scale) * scale;
    float d1 = fp8_round(x[2*w+1] / scale) * scale;
    hh[w] = pack2(d0, d1);
  }
  uint4 o4 = make_uint4(hh[0], hh[1], hh[2], hh[3]);
  *reinterpret_cast<uint4*>(a2 + ((size_t)e*M_ + m)*N2_ + t*8) = o4;
}

extern "C" void kernel_launch(void* const* d_in, const int* in_sizes, int n_in,
                              void* d_out, int out_size, void* d_ws, size_t ws_size,
                              hipStream_t stream)
{
  const float* hs   = (const float*)d_in[0];   // (E,M,K) fp32 holding fp8 values
  const float* hss  = (const float*)d_in[1];   // (E,M,K/128)
  const int*   mm   = (const int*)d_in[2];     // (E,)
  const float* w13  = (const float*)d_in[4];   // (E,N,K)
  const float* w13s = (const float*)d_in[5];   // (E,N/128,K/128)
  const float* w2   = (const float*)d_in[6];   // (E,K,N2)
  const float* w2s  = (const float*)d_in[7];   // (E,K/128,N2/128)

  // d_out is a FLOAT32 buffer (checker reads bf16 high-halves / f32 values).
  // gateup (bf16 u16, 67 MB) lives in its first half, consumed by act_quant
  // before gemm2 overwrites the whole buffer with f32 output.
  u16* gu = (u16*)d_out;
  u16* a2 = (u16*)d_ws;          // a2 (E,M,N2) bf16 in d_ws (16.78 MB)

  gemm_grouped<0, K_, N_><<<dim3(N_/256, M_/256, E_), dim3(512), 0, stream>>>(
      hs, hss, w13, w13s, mm, gu);
  act_quant_kernel<<<dim3(M_, E_), dim3(128), 0, stream>>>(gu, mm, a2);
  gemm_grouped<1, N2_, K_><<<dim3(K_/256, M_/256, E_), dim3(512), 0, stream>>>(
      a2, nullptr, w2, w2s, mm, d_out);
}

// Round 16
// 331.624 us; speedup vs baseline: 1.8484x; 1.1951x over previous
//
#include <hip/hip_runtime.h>
#include <hip/hip_bf16.h>

#define E_  8
#define M_  1024
#define K_  4096
#define N_  2048
#define N2_ 1024

typedef unsigned short u16;
typedef unsigned int   u32;

typedef __bf16 bf16x8 __attribute__((ext_vector_type(8)));
typedef float  f32x4  __attribute__((ext_vector_type(4)));

union FragU { uint4 u; bf16x8 v; };

__device__ __forceinline__ u16 f2bfu(float f){
  union { __hip_bfloat16 h; u16 u; } c;
  c.h = __float2bfloat16(f);   // RNE
  return c.u;
}
__device__ __forceinline__ u32 pack2(float a, float b){
  return (u32)f2bfu(a) | ((u32)f2bfu(b) << 16);
}
__device__ __forceinline__ float bf2f(u16 u){
  u32 x = ((u32)u) << 16;
  return __uint_as_float(x);
}
// f32 whose bits are the RNE-bf16 of f (low mantissa zero) — matches bf16 ref.
__device__ __forceinline__ float bf16val(float f){
  return bf2f(f2bfu(f));
}
__device__ __forceinline__ float fp8_round(float x){
  float ax = fabsf(x);
  if (ax < 0.015625f){
    return rintf(x * 512.0f) * (1.0f/512.0f);
  }
  u32 u = __float_as_uint(x);
  u32 lsb = (u >> 20) & 1u;
  u += 0x7FFFFu + lsb;
  u &= 0xFFF00000u;
  return __uint_as_float(u);
}

// async global->LDS, 16B per lane; LDS dest is wave-uniform base + lane*16.
#define GLD16(g, l) __builtin_amdgcn_global_load_lds( \
    (const __attribute__((address_space(1))) void*)(g), \
    (__attribute__((address_space(3))) void*)(l), 16, 0, 0)

// ---------------------------------------------------------------------------
// Pre-convert hs (fp32 fp8-values) * row-scale -> bf16, XOR-pre-swizzled so
// gemm1 can global_load_lds it linearly and ds_read with chunk^(row&7).
// Chunk c (8 bf16 = 16B); swizzle within each 8-chunk (64-elem) group.
// ---------------------------------------------------------------------------
__global__ __launch_bounds__(512) void conv_hs_kernel(
    const float* __restrict__ hs, const float* __restrict__ hss,
    const int* __restrict__ masked_m, u16* __restrict__ hs16)
{
  const int m = blockIdx.x, e = blockIdx.y;
  if (m >= masked_m[e]) return;
  const int c = threadIdx.x;                       // chunk 0..511
  const float s = hss[((size_t)e*M_ + m)*(K_/128) + (c >> 4)];
  const float* src = hs + ((size_t)e*M_ + m)*K_ + c*8;
  const float4 f0 = *reinterpret_cast<const float4*>(src);
  const float4 f1 = *reinterpret_cast<const float4*>(src + 4);
  uint4 w;
  w.x = pack2(f0.x * s, f0.y * s);
  w.y = pack2(f0.z * s, f0.w * s);
  w.z = pack2(f1.x * s, f1.y * s);
  w.w = pack2(f1.z * s, f1.w * s);
  const int cd = (c & ~7) | ((c & 7) ^ (m & 7));   // pre-swizzled chunk
  *reinterpret_cast<uint4*>(hs16 + ((size_t)e*M_ + m)*K_ + cd*8) = w;
}

// ---------------------------------------------------------------------------
// Grouped masked MFMA GEMM, 128x128 tile, BK=64, 4 waves, dbuf LDS 64KB.
// A: bf16, pre-swizzled, via global_load_lds. B: fp32, reg-staged + converted
// with Wscale folded. C[e][m][n] = sum_k A[e][m][k]*B[e][n][k].
// AMODE 0: C -> gateup bf16 u16. AMODE 1: C -> d_out FLOAT32, masked rows 0.
// ---------------------------------------------------------------------------
template<int AMODE, int KD, int ND>
__global__ __launch_bounds__(256, 2) void gemm_grouped(
    const u16* __restrict__ Abf, const float* __restrict__ Bptr,
    const float* __restrict__ Wscale, const int* __restrict__ masked_m,
    void* __restrict__ Cout)
{
  constexpr int BK  = 64;
  constexpr int KT  = KD / BK;
  constexpr int NKB = KD / 128;
  const int tn = blockIdx.x, tm = blockIdx.y, e = blockIdx.z;
  const int m0 = tm * 128, n0 = tn * 128;
  const int me = masked_m[e];
  const int tid = threadIdx.x;

  u16*   const Cu = (u16*)Cout;
  float* const Cf = (float*)Cout;

  if (m0 >= me){
    if constexpr (AMODE == 1){
      const uint4 z = make_uint4(0u,0u,0u,0u);
      #pragma unroll
      for (int q = 0; q < 16; ++q){
        int idx = tid + 256*q;            // 128 rows x 32 uint4 (128 f32)
        int r = idx >> 5, c = idx & 31;
        *reinterpret_cast<uint4*>(Cf + ((size_t)e*M_ + m0 + r)*ND + n0 + c*4) = z;
      }
    }
    return;
  }

  __shared__ u16 sA[2][128*64];
  __shared__ u16 sB[2][128*64];

  const int lane = tid & 63, wid = tid >> 6;
  const int rrow = tid >> 3;   // 0..31 (B staging row group)
  const int kq   = tid & 7;    // 16B chunk within 64-elem row

  float4 rB[8];
  float  sWv = 0.f;

  auto ISSUE_A = [&](int kt, int buf){
    const int k0 = kt * BK;
    #pragma unroll
    for (int q = 0; q < 4; ++q){
      const int ins = wid*4 + q;                 // 0..15, wave-uniform
      const int r   = ins*8 + (lane >> 3);
      const u16* src = Abf + ((size_t)e*M_ + m0 + r)*KD + k0 + (lane & 7)*8;
      GLD16(src, &sA[buf][ins*512]);
    }
  };

  auto LOAD_B = [&](int kt){
    const int k0 = kt * BK;
    const int kb = k0 >> 7;
    sWv = Wscale[((size_t)e*(ND/128) + tn)*NKB + kb];
    #pragma unroll
    for (int p = 0; p < 4; ++p){
      const int r = p*32 + rrow;
      const float* bp = Bptr + ((size_t)e*ND + n0 + r)*KD + k0 + kq*8;
      rB[2*p]   = *reinterpret_cast<const float4*>(bp);
      rB[2*p+1] = *reinterpret_cast<const float4*>(bp + 4);
    }
  };

  auto WRITE_B = [&](int buf){
    #pragma unroll
    for (int p = 0; p < 4; ++p){
      const int r   = p*32 + rrow;
      const int dst = r*64 + ((kq ^ (r & 7)) * 8);   // XOR-swizzled 16B chunk
      uint4 wb;
      wb.x = pack2(rB[2*p].x * sWv,   rB[2*p].y * sWv);
      wb.y = pack2(rB[2*p].z * sWv,   rB[2*p].w * sWv);
      wb.z = pack2(rB[2*p+1].x * sWv, rB[2*p+1].y * sWv);
      wb.w = pack2(rB[2*p+1].z * sWv, rB[2*p+1].w * sWv);
      *reinterpret_cast<uint4*>(&sB[buf][dst]) = wb;
    }
  };

  const int wm = wid >> 1, wn = wid & 1;   // 2x2 waves, each owns 64x64
  const int fr = lane & 15, kg = lane >> 4;

  f32x4 acc[4][4];
  #pragma unroll
  for (int i = 0; i < 4; ++i)
    #pragma unroll
    for (int j = 0; j < 4; ++j)
      acc[i][j] = (f32x4){0.f, 0.f, 0.f, 0.f};

  auto COMPUTE = [&](int buf){
    #pragma unroll
    for (int ks = 0; ks < 2; ++ks){
      FragU av[4], bv[4];
      #pragma unroll
      for (int i = 0; i < 4; ++i){
        const int r  = wm*64 + i*16 + fr;
        const int ch = (ks*4 + kg) ^ (r & 7);
        av[i].u = *reinterpret_cast<const uint4*>(&sA[buf][r*64 + ch*8]);
      }
      #pragma unroll
      for (int j = 0; j < 4; ++j){
        const int r  = wn*64 + j*16 + fr;
        const int ch = (ks*4 + kg) ^ (r & 7);
        bv[j].u = *reinterpret_cast<const uint4*>(&sB[buf][r*64 + ch*8]);
      }
      #pragma unroll
      for (int i = 0; i < 4; ++i)
        #pragma unroll
        for (int j = 0; j < 4; ++j)
          acc[i][j] = __builtin_amdgcn_mfma_f32_16x16x32_bf16(av[i].v, bv[j].v, acc[i][j], 0, 0, 0);
    }
  };

  ISSUE_A(0, 0);
  LOAD_B(0);
  WRITE_B(0);
  __syncthreads();                 // drains gld_lds(0) too
  int cur = 0;
  for (int kt = 0; kt < KT; ++kt){
    if (kt + 1 < KT){
      ISSUE_A(kt + 1, cur ^ 1);    // async into other buffer
      LOAD_B(kt + 1);
    }
    COMPUTE(cur);
    if (kt + 1 < KT) WRITE_B(cur ^ 1);
    __syncthreads();               // drains vmem (incl. gld_lds) + lds
    cur ^= 1;
  }

  #pragma unroll
  for (int i = 0; i < 4; ++i){
    #pragma unroll
    for (int j = 0; j < 4; ++j){
      #pragma unroll
      for (int r = 0; r < 4; ++r){
        const int gm = m0 + wm*64 + i*16 + kg*4 + r;
        const int gn = n0 + wn*64 + j*16 + fr;
        if constexpr (AMODE == 0){
          if (gm < me) Cu[((size_t)e*M_ + gm)*ND + gn] = f2bfu(acc[i][j][r]);
        } else {
          const float v = (gm < me) ? bf16val(acc[i][j][r]) : 0.0f;
          Cf[((size_t)e*M_ + gm)*ND + gn] = v;
        }
      }
    }
  }
}

// SiLU(gate)*up, per-128 amax -> fp8 quant -> dequant bf16; a2 written
// PRE-SWIZZLED (chunk ^ (row&7) within 8-chunk groups) for gemm2's gld_lds.
__global__ __launch_bounds__(128) void act_quant_kernel(
    const u16* __restrict__ gu, const int* __restrict__ masked_m,
    u16* __restrict__ a2)
{
  const int m = blockIdx.x, e = blockIdx.y;
  if (m >= masked_m[e]) return;
  const int t = threadIdx.x;
  const u16* row = gu + ((size_t)e*M_ + m)*N_;
  uint4 g4 = *reinterpret_cast<const uint4*>(row + t*8);
  uint4 u4 = *reinterpret_cast<const uint4*>(row + N2_ + t*8);
  u32 gp[4] = {g4.x, g4.y, g4.z, g4.w};
  u32 up[4] = {u4.x, u4.y, u4.z, u4.w};

  float x[8];
  #pragma unroll
  for (int w = 0; w < 4; ++w){
    float g0 = bf2f((u16)(gp[w] & 0xffffu));
    float g1 = bf2f((u16)(gp[w] >> 16));
    float u0 = bf2f((u16)(up[w] & 0xffffu));
    float u1 = bf2f((u16)(up[w] >> 16));
    x[2*w]   = g0 / (1.0f + expf(-g0)) * u0;
    x[2*w+1] = g1 / (1.0f + expf(-g1)) * u1;
  }

  float amax = 0.f;
  #pragma unroll
  for (int k = 0; k < 8; ++k) amax = fmaxf(amax, fabsf(x[k]));
  #pragma unroll
  for (int o = 8; o > 0; o >>= 1) amax = fmaxf(amax, __shfl_xor(amax, o, 16));
  const float scale = fmaxf(amax, 1e-10f) / 448.0f;

  u32 hh[4];
  #pragma unroll
  for (int w = 0; w < 4; ++w){
    float d0 = fp8_round(x[2*w]   / scale) * scale;
    float d1 = fp8_round(x[2*w+1] / scale) * scale;
    hh[w] = pack2(d0, d1);
  }
  uint4 o4 = make_uint4(hh[0], hh[1], hh[2], hh[3]);
  const int td = (t & ~7) | ((t & 7) ^ (m & 7));   // pre-swizzled chunk
  *reinterpret_cast<uint4*>(a2 + ((size_t)e*M_ + m)*N2_ + td*8) = o4;
}

extern "C" void kernel_launch(void* const* d_in, const int* in_sizes, int n_in,
                              void* d_out, int out_size, void* d_ws, size_t ws_size,
                              hipStream_t stream)
{
  const float* hs   = (const float*)d_in[0];   // (E,M,K) fp32 holding fp8 values
  const float* hss  = (const float*)d_in[1];   // (E,M,K/128)
  const int*   mm   = (const int*)d_in[2];     // (E,)
  const float* w13  = (const float*)d_in[4];   // (E,N,K)
  const float* w13s = (const float*)d_in[5];   // (E,N/128,K/128)
  const float* w2   = (const float*)d_in[6];   // (E,K,N2)
  const float* w2s  = (const float*)d_in[7];   // (E,K/128,N2/128)

  // d_out is a FLOAT32 buffer (134 MB), checker reads bf16 high-halves.
  // Layout during pipeline (all dead before gemm2's full overwrite):
  //   [0, 33.5 MB)      gateup bf16 u16 (E*M*N = 16.78M elems)
  //   [33.5, 100.6 MB)  hs16 bf16 u16, pre-swizzled (E*M*K = 33.5M elems)
  u16* gu   = (u16*)d_out;
  u16* hs16 = (u16*)d_out + (size_t)E_*M_*N_;
  u16* a2   = (u16*)d_ws;        // (E,M,N2) bf16, pre-swizzled (16.78 MB)

  conv_hs_kernel<<<dim3(M_, E_), dim3(512), 0, stream>>>(hs, hss, mm, hs16);
  gemm_grouped<0, K_, N_><<<dim3(N_/128, M_/128, E_), dim3(256), 0, stream>>>(
      hs16, w13, w13s, mm, gu);
  act_quant_kernel<<<dim3(M_, E_), dim3(128), 0, stream>>>(gu, mm, a2);
  gemm_grouped<1, N2_, K_><<<dim3(K_/128, M_/128, E_), dim3(256), 0, stream>>>(
      a2, w2, w2s, mm, d_out);
}

// Round 17
// 293.431 us; speedup vs baseline: 2.0890x; 1.1302x over previous
//
#include <hip/hip_runtime.h>
#include <hip/hip_bf16.h>

#define E_  8
#define M_  1024
#define K_  4096
#define N_  2048
#define N2_ 1024

typedef unsigned short u16;
typedef unsigned char  u8;
typedef unsigned int   u32;
typedef long           i64;   // 64-bit on amdgcn

typedef __bf16 bf16x8 __attribute__((ext_vector_type(8)));
typedef float  f32x4  __attribute__((ext_vector_type(4)));

union FragU { uint4 u; bf16x8 v; };

__device__ __forceinline__ u16 f2bfu(float f){
  union { __hip_bfloat16 h; u16 u; } c;
  c.h = __float2bfloat16(f);   // RNE
  return c.u;
}
__device__ __forceinline__ u32 pack2(float a, float b){
  return (u32)f2bfu(a) | ((u32)f2bfu(b) << 16);
}
__device__ __forceinline__ float bf2f(u16 u){
  u32 x = ((u32)u) << 16;
  return __uint_as_float(x);
}
__device__ __forceinline__ float bf16val(float f){
  return bf2f(f2bfu(f));
}
__device__ __forceinline__ float fp8_round(float x){
  float ax = fabsf(x);
  if (ax < 0.015625f){
    return rintf(x * 512.0f) * (1.0f/512.0f);
  }
  u32 u = __float_as_uint(x);
  u32 lsb = (u >> 20) & 1u;
  u += 0x7FFFFu + lsb;
  u &= 0xFFF00000u;
  return __uint_as_float(u);
}
// exact fp32 -> fp8 e4m3fn byte (value guaranteed on the fp8 grid, |v|<=448)
__device__ __forceinline__ u32 f2fp8(float v){
  u32 b = __float_as_uint(v);
  u32 s = (b >> 24) & 0x80u;
  int e = (int)((b >> 23) & 0xffu);
  u32 m = (b >> 20) & 7u;
  if (e >= 121) return s | ((u32)(e - 120) << 3) | m;   // normal
  return s | (u32)(fabsf(v) * 512.0f + 0.25f);          // subnormal / zero
}

// async global->LDS, 16B per lane; LDS dest = wave-uniform base + lane*16.
#define GLD16(g, l) __builtin_amdgcn_global_load_lds( \
    (const __attribute__((address_space(1))) void*)(g), \
    (__attribute__((address_space(3))) void*)(l), 16, 0, 0)

// ---------------------------------------------------------------------------
// fp32 (fp8-grid values) -> raw fp8 bytes, XOR-pre-swizzled in 16B chunks
// within each 8-chunk (128B) group so gemm kernels can gld_lds linearly and
// ds_read with chunk^(row&7). Row stride K_=4096 for both hs and w13.
// ---------------------------------------------------------------------------
template<bool MASKED>
__global__ __launch_bounds__(256) void conv8_kernel(
    const float* __restrict__ src_, const int* __restrict__ masked_m,
    u8* __restrict__ dst)
{
  const int row = blockIdx.x, e = blockIdx.y;
  if (MASKED && row >= masked_m[e]) return;
  const int t = threadIdx.x;                 // 16B chunk 0..255
  const size_t R = (size_t)e*gridDim.x + row;
  const float* s = src_ + R*K_ + t*16;
  const float4 f0 = *reinterpret_cast<const float4*>(s);
  const float4 f1 = *reinterpret_cast<const float4*>(s + 4);
  const float4 f2 = *reinterpret_cast<const float4*>(s + 8);
  const float4 f3 = *reinterpret_cast<const float4*>(s + 12);
  uint4 w;
  w.x = f2fp8(f0.x) | (f2fp8(f0.y)<<8) | (f2fp8(f0.z)<<16) | (f2fp8(f0.w)<<24);
  w.y = f2fp8(f1.x) | (f2fp8(f1.y)<<8) | (f2fp8(f1.z)<<16) | (f2fp8(f1.w)<<24);
  w.z = f2fp8(f2.x) | (f2fp8(f2.y)<<8) | (f2fp8(f2.z)<<16) | (f2fp8(f2.w)<<24);
  w.w = f2fp8(f3.x) | (f2fp8(f3.y)<<8) | (f2fp8(f3.z)<<16) | (f2fp8(f3.w)<<24);
  const int td = (t & ~7) | ((t & 7) ^ (row & 7));
  *reinterpret_cast<uint4*>(dst + R*K_ + td*16) = w;
}

// ---------------------------------------------------------------------------
// gemm1: fp8 x fp8 with per-128-block scale fixup (DeepGEMM style).
// 128x128 tile, BK=128 (= one scale block), KT=32, 4 waves, dbuf LDS 65KB.
// gateup[e][m][n] = sum_kb sa[m][kb]*sw[n/128][kb] * (sum_{k in kb} a8*b8)
// Both operands via global_load_lds from pre-swizzled fp8 buffers.
// ---------------------------------------------------------------------------
__global__ __launch_bounds__(256, 2) void gemm1_fp8(
    const u8* __restrict__ A8, const float* __restrict__ Ascale,
    const u8* __restrict__ B8, const float* __restrict__ Wscale,
    const int* __restrict__ masked_m, u16* __restrict__ Cu)
{
  const int tn = blockIdx.x, tm = blockIdx.y, e = blockIdx.z;
  const int m0 = tm*128, n0 = tn*128;
  const int me = masked_m[e];
  if (m0 >= me) return;
  const int tid = threadIdx.x;
  const int lane = tid & 63, wid = tid >> 6;

  __shared__ u8 sA[2][128*128];
  __shared__ u8 sB[2][128*128];
  __shared__ float sSa[2][128];

  const size_t rbA = (size_t)e*M_ + m0;
  const size_t rbB = (size_t)e*N_ + n0;

  auto ISSUE = [&](const u8* G, size_t rowbase, int kt, u8* Sbuf){
    #pragma unroll
    for (int q = 0; q < 4; ++q){
      const int ins = wid*4 + q;               // 0..15 per block
      const int r   = ins*8 + (lane >> 3);
      const u8* src = G + (rowbase + r)*K_ + kt*128 + (lane & 7)*16;
      GLD16(src, Sbuf + ins*1024);
    }
  };
  auto STAGE_SA = [&](int kt, int buf){
    if (tid < 128) sSa[buf][tid] = Ascale[(rbA + tid)*32 + kt];
  };

  const int wm = wid >> 1, wn = wid & 1;   // 2x2 waves, 64x64 each
  const int fr = lane & 15, kg = lane >> 4;

  f32x4 acc[4][4];
  #pragma unroll
  for (int i = 0; i < 4; ++i)
    #pragma unroll
    for (int j = 0; j < 4; ++j)
      acc[i][j] = (f32x4){0.f, 0.f, 0.f, 0.f};

  auto COMPUTE = [&](int buf, float sw){
    f32x4 blk[4][4];
    #pragma unroll
    for (int ks = 0; ks < 4; ++ks){           // 4 x K=32 within the 128-block
      i64 av[4], bv[4];
      #pragma unroll
      for (int i = 0; i < 4; ++i){
        const int r   = wm*64 + i*16 + fr;
        const int c16 = ks*2 + (kg >> 1);
        const int ad  = r*128 + ((c16 ^ (r & 7)) << 4) + ((kg & 1) << 3);
        av[i] = *reinterpret_cast<const i64*>(&sA[buf][ad]);
      }
      #pragma unroll
      for (int j = 0; j < 4; ++j){
        const int r   = wn*64 + j*16 + fr;
        const int c16 = ks*2 + (kg >> 1);
        const int ad  = r*128 + ((c16 ^ (r & 7)) << 4) + ((kg & 1) << 3);
        bv[j] = *reinterpret_cast<const i64*>(&sB[buf][ad]);
      }
      #pragma unroll
      for (int i = 0; i < 4; ++i)
        #pragma unroll
        for (int j = 0; j < 4; ++j){
          f32x4 cin = (ks == 0) ? (f32x4){0.f,0.f,0.f,0.f} : blk[i][j];
          blk[i][j] = __builtin_amdgcn_mfma_f32_16x16x32_fp8_fp8(av[i], bv[j], cin, 0, 0, 0);
        }
    }
    // fixup: acc += (sa[row] * sw) * blk   (exact f32 scale application)
    #pragma unroll
    for (int i = 0; i < 4; ++i){
      f32x4 sa = *reinterpret_cast<const f32x4*>(&sSa[buf][wm*64 + i*16 + kg*4]);
      sa *= sw;
      #pragma unroll
      for (int j = 0; j < 4; ++j)
        acc[i][j] += sa * blk[i][j];
    }
  };

  float sw = Wscale[((size_t)e*16 + tn)*32 + 0];
  ISSUE(A8, rbA, 0, sA[0]);
  ISSUE(B8, rbB, 0, sB[0]);
  STAGE_SA(0, 0);
  __syncthreads();
  int cur = 0;
  for (int kt = 0; kt < 32; ++kt){
    float sw_next = 0.f;
    if (kt + 1 < 32){
      ISSUE(A8, rbA, kt + 1, sA[cur ^ 1]);
      ISSUE(B8, rbB, kt + 1, sB[cur ^ 1]);
      STAGE_SA(kt + 1, cur ^ 1);
      sw_next = Wscale[((size_t)e*16 + tn)*32 + kt + 1];
    }
    COMPUTE(cur, sw);
    __syncthreads();
    cur ^= 1; sw = sw_next;
  }

  #pragma unroll
  for (int i = 0; i < 4; ++i){
    #pragma unroll
    for (int j = 0; j < 4; ++j){
      #pragma unroll
      for (int r = 0; r < 4; ++r){
        const int gm = m0 + wm*64 + i*16 + kg*4 + r;
        const int gn = n0 + wn*64 + j*16 + fr;
        if (gm < me) Cu[((size_t)e*M_ + gm)*N_ + gn] = f2bfu(acc[i][j][r]);
      }
    }
  }
}

// ---------------------------------------------------------------------------
// gemm2 (unchanged R16 path): A = a2 bf16 pre-swizzled via gld_lds;
// B = w2 fp32 reg-staged with Wscale folded to bf16. Output FLOAT32.
// ---------------------------------------------------------------------------
template<int KD, int ND>
__global__ __launch_bounds__(256, 2) void gemm2_bf16(
    const u16* __restrict__ Abf, const float* __restrict__ Bptr,
    const float* __restrict__ Wscale, const int* __restrict__ masked_m,
    float* __restrict__ Cf)
{
  constexpr int BK  = 64;
  constexpr int KT  = KD / BK;
  constexpr int NKB = KD / 128;
  const int tn = blockIdx.x, tm = blockIdx.y, e = blockIdx.z;
  const int m0 = tm * 128, n0 = tn * 128;
  const int me = masked_m[e];
  const int tid = threadIdx.x;

  if (m0 >= me){
    const uint4 z = make_uint4(0u,0u,0u,0u);
    #pragma unroll
    for (int q = 0; q < 16; ++q){
      int idx = tid + 256*q;
      int r = idx >> 5, c = idx & 31;
      *reinterpret_cast<uint4*>(Cf + ((size_t)e*M_ + m0 + r)*ND + n0 + c*4) = z;
    }
    return;
  }

  __shared__ u16 sA[2][128*64];
  __shared__ u16 sB[2][128*64];

  const int lane = tid & 63, wid = tid >> 6;
  const int rrow = tid >> 3;
  const int kq   = tid & 7;

  float4 rB[8];
  float  sWv = 0.f;

  auto ISSUE_A = [&](int kt, int buf){
    const int k0 = kt * BK;
    #pragma unroll
    for (int q = 0; q < 4; ++q){
      const int ins = wid*4 + q;
      const int r   = ins*8 + (lane >> 3);
      const u16* src = Abf + ((size_t)e*M_ + m0 + r)*KD + k0 + (lane & 7)*8;
      GLD16(src, &sA[buf][ins*512]);
    }
  };
  auto LOAD_B = [&](int kt){
    const int k0 = kt * BK;
    const int kb = k0 >> 7;
    sWv = Wscale[((size_t)e*(ND/128) + tn)*NKB + kb];
    #pragma unroll
    for (int p = 0; p < 4; ++p){
      const int r = p*32 + rrow;
      const float* bp = Bptr + ((size_t)e*ND + n0 + r)*KD + k0 + kq*8;
      rB[2*p]   = *reinterpret_cast<const float4*>(bp);
      rB[2*p+1] = *reinterpret_cast<const float4*>(bp + 4);
    }
  };
  auto WRITE_B = [&](int buf){
    #pragma unroll
    for (int p = 0; p < 4; ++p){
      const int r   = p*32 + rrow;
      const int dst = r*64 + ((kq ^ (r & 7)) * 8);
      uint4 wb;
      wb.x = pack2(rB[2*p].x * sWv,   rB[2*p].y * sWv);
      wb.y = pack2(rB[2*p].z * sWv,   rB[2*p].w * sWv);
      wb.z = pack2(rB[2*p+1].x * sWv, rB[2*p+1].y * sWv);
      wb.w = pack2(rB[2*p+1].z * sWv, rB[2*p+1].w * sWv);
      *reinterpret_cast<uint4*>(&sB[buf][dst]) = wb;
    }
  };

  const int wm = wid >> 1, wn = wid & 1;
  const int fr = lane & 15, kg = lane >> 4;

  f32x4 acc[4][4];
  #pragma unroll
  for (int i = 0; i < 4; ++i)
    #pragma unroll
    for (int j = 0; j < 4; ++j)
      acc[i][j] = (f32x4){0.f, 0.f, 0.f, 0.f};

  auto COMPUTE = [&](int buf){
    #pragma unroll
    for (int ks = 0; ks < 2; ++ks){
      FragU av[4], bv[4];
      #pragma unroll
      for (int i = 0; i < 4; ++i){
        const int r  = wm*64 + i*16 + fr;
        const int ch = (ks*4 + kg) ^ (r & 7);
        av[i].u = *reinterpret_cast<const uint4*>(&sA[buf][r*64 + ch*8]);
      }
      #pragma unroll
      for (int j = 0; j < 4; ++j){
        const int r  = wn*64 + j*16 + fr;
        const int ch = (ks*4 + kg) ^ (r & 7);
        bv[j].u = *reinterpret_cast<const uint4*>(&sB[buf][r*64 + ch*8]);
      }
      #pragma unroll
      for (int i = 0; i < 4; ++i)
        #pragma unroll
        for (int j = 0; j < 4; ++j)
          acc[i][j] = __builtin_amdgcn_mfma_f32_16x16x32_bf16(av[i].v, bv[j].v, acc[i][j], 0, 0, 0);
    }
  };

  ISSUE_A(0, 0);
  LOAD_B(0);
  WRITE_B(0);
  __syncthreads();
  int cur = 0;
  for (int kt = 0; kt < KT; ++kt){
    if (kt + 1 < KT){
      ISSUE_A(kt + 1, cur ^ 1);
      LOAD_B(kt + 1);
    }
    COMPUTE(cur);
    if (kt + 1 < KT) WRITE_B(cur ^ 1);
    __syncthreads();
    cur ^= 1;
  }

  #pragma unroll
  for (int i = 0; i < 4; ++i){
    #pragma unroll
    for (int j = 0; j < 4; ++j){
      #pragma unroll
      for (int r = 0; r < 4; ++r){
        const int gm = m0 + wm*64 + i*16 + kg*4 + r;
        const int gn = n0 + wn*64 + j*16 + fr;
        const float v = (gm < me) ? bf16val(acc[i][j][r]) : 0.0f;
        Cf[((size_t)e*M_ + gm)*ND + gn] = v;
      }
    }
  }
}

// SiLU(gate)*up, per-128 amax -> fp8 quant -> dequant bf16; a2 pre-swizzled.
__global__ __launch_bounds__(128) void act_quant_kernel(
    const u16* __restrict__ gu, const int* __restrict__ masked_m,
    u16* __restrict__ a2)
{
  const int m = blockIdx.x, e = blockIdx.y;
  if (m >= masked_m[e]) return;
  const int t = threadIdx.x;
  const u16* row = gu + ((size_t)e*M_ + m)*N_;
  uint4 g4 = *reinterpret_cast<const uint4*>(row + t*8);
  uint4 u4 = *reinterpret_cast<const uint4*>(row + N2_ + t*8);
  u32 gp[4] = {g4.x, g4.y, g4.z, g4.w};
  u32 up[4] = {u4.x, u4.y, u4.z, u4.w};

  float x[8];
  #pragma unroll
  for (int w = 0; w < 4; ++w){
    float g0 = bf2f((u16)(gp[w] & 0xffffu));
    float g1 = bf2f((u16)(gp[w] >> 16));
    float u0 = bf2f((u16)(up[w] & 0xffffu));
    float u1 = bf2f((u16)(up[w] >> 16));
    x[2*w]   = g0 / (1.0f + expf(-g0)) * u0;
    x[2*w+1] = g1 / (1.0f + expf(-g1)) * u1;
  }

  float amax = 0.f;
  #pragma unroll
  for (int k = 0; k < 8; ++k) amax = fmaxf(amax, fabsf(x[k]));
  #pragma unroll
  for (int o = 8; o > 0; o >>= 1) amax = fmaxf(amax, __shfl_xor(amax, o, 16));
  const float scale = fmaxf(amax, 1e-10f) / 448.0f;

  u32 hh[4];
  #pragma unroll
  for (int w = 0; w < 4; ++w){
    float d0 = fp8_round(x[2*w]   / scale) * scale;
    float d1 = fp8_round(x[2*w+1] / scale) * scale;
    hh[w] = pack2(d0, d1);
  }
  uint4 o4 = make_uint4(hh[0], hh[1], hh[2], hh[3]);
  const int td = (t & ~7) | ((t & 7) ^ (m & 7));
  *reinterpret_cast<uint4*>(a2 + ((size_t)e*M_ + m)*N2_ + td*8) = o4;
}

extern "C" void kernel_launch(void* const* d_in, const int* in_sizes, int n_in,
                              void* d_out, int out_size, void* d_ws, size_t ws_size,
                              hipStream_t stream)
{
  const float* hs   = (const float*)d_in[0];   // (E,M,K) fp32 holding fp8 values
  const float* hss  = (const float*)d_in[1];   // (E,M,K/128)
  const int*   mm   = (const int*)d_in[2];     // (E,)
  const float* w13  = (const float*)d_in[4];   // (E,N,K)
  const float* w13s = (const float*)d_in[5];   // (E,N/128,K/128)
  const float* w2   = (const float*)d_in[6];   // (E,K,N2)
  const float* w2s  = (const float*)d_in[7];   // (E,K/128,N2/128)

  // d_out is a FLOAT32 buffer (134.2 MB); checker reads bf16 high-halves.
  // Pipeline layout (exact fit, all dead before gemm2's full overwrite):
  //   [0,        33.5 MB)  gateup bf16 u16  (E*M*N elems)
  //   [33.5 MB,  67.1 MB)  hs8  fp8 bytes, pre-swizzled (E*M*K)
  //   [67.1 MB, 134.2 MB)  w13_8 fp8 bytes, pre-swizzled (E*N*K)
  u16* gu    = (u16*)d_out;
  u8*  hs8   = (u8*)d_out + (size_t)E_*M_*N_*2;
  u8*  w13_8 = (u8*)d_out + (size_t)E_*M_*N_*2 + (size_t)E_*M_*K_;
  u16* a2    = (u16*)d_ws;       // (E,M,N2) bf16, pre-swizzled (16.78 MB)

  conv8_kernel<true> <<<dim3(M_, E_), dim3(256), 0, stream>>>(hs,  mm, hs8);
  conv8_kernel<false><<<dim3(N_, E_), dim3(256), 0, stream>>>(w13, mm, w13_8);
  gemm1_fp8<<<dim3(N_/128, M_/128, E_), dim3(256), 0, stream>>>(
      hs8, hss, w13_8, w13s, mm, gu);
  act_quant_kernel<<<dim3(M_, E_), dim3(128), 0, stream>>>(gu, mm, a2);
  gemm2_bf16<N2_, K_><<<dim3(K_/128, M_/128, E_), dim3(256), 0, stream>>>(
      a2, w2, w2s, mm, (float*)d_out);
}